// Round 7
// baseline (87.396 us; speedup 1.0000x reference)
//
#include <hip/hip_runtime.h>
#include <math.h>

#define HID 64
#define BKT_SHIFT 13                 // 8192 nodes per bucket
#define BKT_RANGE 8192
#define CCHUNK 32                    // wave-chunks per bucket in phase B

typedef __attribute__((ext_vector_type(8))) short short8;
typedef __attribute__((ext_vector_type(4))) float f32x4;
typedef unsigned long long ull;

union FragU {
    uint4 q;
    short8 v;
    uint32_t u[4];
};

__device__ __forceinline__ uint32_t cvt_pk_bf16(float lo, float hi) {
    uint32_t r;
    asm("v_cvt_pk_bf16_f32 %0, %1, %2" : "=v"(r) : "v"(lo), "v"(hi));
    return r;
}
__device__ __forceinline__ float bf16lo_f(uint32_t u) { return __uint_as_float(u << 16); }
__device__ __forceinline__ float bf16hi_f(uint32_t u) { return __uint_as_float(u & 0xFFFF0000u); }
__device__ __forceinline__ unsigned short bf16_of(float v) {
    return (unsigned short)(cvt_pk_bf16(v, 0.f) & 0xFFFFu);
}

// ---------------------------------------------------------------------------
// Prep: bf16-transposed weights so MFMA A-frags are single 16B loads.
// w2T/nw2T/mw2T: [j][k] bf16 (64x64).  w1x: [j][8] = {w1[0][j],w1[1][j],
// w1[2][j], b1[j], 0...}; nw1x: {nw1[0][j],nw1[1][j],nb1[j],0...};
// mw1x: {mw1[j], mb1[j], 0...}.  Bias folded into K (input slot = 1.0).
// ---------------------------------------------------------------------------
__global__ void prep_kernel(
    const float* __restrict__ w1,  const float* __restrict__ b1,  const float* __restrict__ w2,
    const float* __restrict__ nw1, const float* __restrict__ nb1, const float* __restrict__ nw2,
    const float* __restrict__ mw1, const float* __restrict__ mb1, const float* __restrict__ mw2,
    unsigned short* __restrict__ w1x,  unsigned short* __restrict__ w2T,
    unsigned short* __restrict__ nw1x, unsigned short* __restrict__ nw2T,
    unsigned short* __restrict__ mw1x, unsigned short* __restrict__ mw2T)
{
    int t = blockIdx.x * 256 + threadIdx.x;
    if (t < 4096) {
        int j = t >> 6, k = t & 63;
        w2T [t] = bf16_of(w2 [k * HID + j]);
        nw2T[t] = bf16_of(nw2[k * HID + j]);
        mw2T[t] = bf16_of(mw2[k * HID + j]);
    }
    if (t < 512) {
        int j = t >> 3, k = t & 7;
        float ve = k == 0 ? w1[j] : k == 1 ? w1[HID + j] : k == 2 ? w1[2 * HID + j] : k == 3 ? b1[j] : 0.f;
        float vn = k == 0 ? nw1[j] : k == 1 ? nw1[HID + j] : k == 2 ? nb1[j] : 0.f;
        float vm = k == 0 ? mw1[j] : k == 1 ? mb1[j] : 0.f;
        w1x [t] = bf16_of(ve);
        nw1x[t] = bf16_of(vn);
        mw1x[t] = bf16_of(vm);
    }
}

// ---------------------------------------------------------------------------
// Edge v3: BOTH layers on MFMA.  Per wave = 64 edges, 4 sets of 16.
// L1: B-frag = [a,b,c,1] (3 shfl), A = w1x -> 4 MFMA -> relu/cvt -> 2KB/wave
// LDS tile (b64 swizzle, floor-conflict-free) -> L2 B-frags -> 8 MFMA ->
// relu.w3 epilogue -> bucket append (mode 0) / atomic fallback (mode 1).
// ---------------------------------------------------------------------------
__global__ __launch_bounds__(256, 4) void edge_mfma2_kernel(
    const float* __restrict__ nf, const float* __restrict__ ef,
    const int* __restrict__ src, const int* __restrict__ dst,
    const unsigned short* __restrict__ w1x, const unsigned short* __restrict__ w2T,
    const float* __restrict__ b2, const float* __restrict__ w3, const float* __restrict__ b3,
    uint2* __restrict__ recs, ull* __restrict__ offs,
    float* __restrict__ aggFb, int E, int B, int mode)
{
    __shared__ uint2 tile[4][16][16];   // per wave: 16 rows x 128B

    const int tid  = threadIdx.x;
    const int lane = tid & 63;
    const int wid  = tid >> 6;
    const int g    = lane >> 4;
    const int eL   = lane & 15;

    // ---- frags: single 16B loads from prepped weights ----
    FragU af1[4];
#pragma unroll
    for (int t = 0; t < 4; ++t) {
        uint4 q = *(const uint4*)&w1x[(t * 16 + eL) * 8];
        af1[t].q = (g == 0) ? q : make_uint4(0, 0, 0, 0);
    }
    FragU af2[4][2];
#pragma unroll
    for (int t = 0; t < 4; ++t)
#pragma unroll
        for (int h = 0; h < 2; ++h)
            af2[t][h].q = *(const uint4*)&w2T[(t * 16 + eL) * 64 + h * 32 + g * 8];

    f32x4 b2v4[4];
    uint32_t w3p[8];
#pragma unroll
    for (int t = 0; t < 4; ++t) {
        int j = t * 16 + g * 4;
        b2v4[t] = *(const f32x4*)&b2[j];
        f32x4 wv = *(const f32x4*)&w3[j];
        w3p[2 * t]     = cvt_pk_bf16(wv[0], wv[1]);
        w3p[2 * t + 1] = cvt_pk_bf16(wv[2], wv[3]);
    }
    const float b3c = b3[0];

    const int e0   = blockIdx.x * 256;
    const int eidx = e0 + tid;
    const int ei   = eidx < E ? eidx : E - 1;
    const int dmine = dst[ei];
    const float a = nf[src[ei]];
    const float b = nf[dmine];
    const float c = ef[ei];

    float mymsg = 0.f;

#pragma unroll
    for (int s = 0; s < 4; ++s) {
        float av = __shfl(a, s * 16 + eL);
        float bv = __shfl(b, s * 16 + eL);
        float cv = __shfl(c, s * 16 + eL);
        FragU bin;
        bin.u[0] = (g == 0) ? cvt_pk_bf16(av, bv) : 0u;
        bin.u[1] = (g == 0) ? cvt_pk_bf16(cv, 1.0f) : 0u;
        bin.u[2] = 0u; bin.u[3] = 0u;

        // layer 1: 4 MFMA -> relu -> bf16 -> LDS tile
#pragma unroll
        for (int t = 0; t < 4; ++t) {
            f32x4 h4 = __builtin_amdgcn_mfma_f32_16x16x32_bf16(
                af1[t].v, bin.v, (f32x4){0.f, 0.f, 0.f, 0.f}, 0, 0, 0);
            uint32_t p0 = cvt_pk_bf16(fmaxf(h4[0], 0.f), fmaxf(h4[1], 0.f));
            uint32_t p1 = cvt_pk_bf16(fmaxf(h4[2], 0.f), fmaxf(h4[3], 0.f));
            tile[wid][eL][(4 * t + g) ^ ((eL & 7) << 1)] = make_uint2(p0, p1);
        }

        // layer 2 B-frags from tile (16B chunks, same swizzle family)
        FragU bf0, bf1;
        {
            const uint4* row = (const uint4*)&tile[wid][eL][0];
            bf0.q = row[(g)     ^ (eL & 7)];
            bf1.q = row[(4 + g) ^ (eL & 7)];
        }

        float p = 0.f;
#pragma unroll
        for (int t = 0; t < 4; ++t) {
            f32x4 ac = __builtin_amdgcn_mfma_f32_16x16x32_bf16(af2[t][0].v, bf0.v, b2v4[t], 0, 0, 0);
            ac = __builtin_amdgcn_mfma_f32_16x16x32_bf16(af2[t][1].v, bf1.v, ac, 0, 0, 0);
            p = fmaf(fmaxf(ac[0], 0.f), bf16lo_f(w3p[2 * t]),     p);
            p = fmaf(fmaxf(ac[1], 0.f), bf16hi_f(w3p[2 * t]),     p);
            p = fmaf(fmaxf(ac[2], 0.f), bf16lo_f(w3p[2 * t + 1]), p);
            p = fmaf(fmaxf(ac[3], 0.f), bf16hi_f(w3p[2 * t + 1]), p);
        }
        p += __shfl_xor(p, 16);
        p += __shfl_xor(p, 32);
        if (s == g) mymsg = p + b3c;   // lane's own edge: lane = s*16+eL with s==g
    }

    const bool valid = eidx < E;

    if (mode == 1) {
        if (valid) atomicAdd(&aggFb[dmine], mymsg);
        return;
    }

    // ---- bucket append: group 64 edges by bucket, coalesced wave-private write ----
    const int bkt = dmine >> BKT_SHIFT;
    const ull lt = (1ull << lane) - 1;
    int myslot = 0;
    int off = 0;
    uint32_t pack_lo = 0, pack_hi = 0;
    for (int b = 0; b < B; ++b) {
        if (b < 4) pack_lo |= (uint32_t)off << (8 * b);
        else       pack_hi |= (uint32_t)off << (8 * (b - 4));
        ull m = __ballot(valid && bkt == b);
        if (valid && bkt == b) myslot = off + (int)__popcll(m & lt);
        off += (int)__popcll(m);
    }
    pack_hi |= (uint32_t)off << 24;

    const size_t wgl = (size_t)blockIdx.x * 4 + wid;
    if (valid) recs[wgl * 64 + myslot] = make_uint2((uint32_t)dmine, __float_as_uint(mymsg));
    if (lane == 0) offs[wgl] = ((ull)pack_hi << 32) | (ull)pack_lo;
}

// ---------------------------------------------------------------------------
// Phase B: block (b,c) accumulates bucket b's records from wave-chunk c into
// a 32KB LDS array (LDS atomics), then writes a dense partial plane.
// ---------------------------------------------------------------------------
__global__ __launch_bounds__(256) void bucket_accum_kernel(
    const uint2* __restrict__ recs, const ull* __restrict__ offs,
    float* __restrict__ partial, int NW, int B)
{
    __shared__ float acc[BKT_RANGE];

    const int b = blockIdx.x / CCHUNK;
    const int c = blockIdx.x % CCHUNK;

    for (int i = threadIdx.x; i < BKT_RANGE; i += 256) acc[i] = 0.f;
    __syncthreads();

    const int wpc = (NW + CCHUNK - 1) / CCHUNK;
    const int w0 = c * wpc;
    const int w1 = (w0 + wpc < NW) ? w0 + wpc : NW;
    const int nb = b + 1;
    const int base_node = b << BKT_SHIFT;

    for (int w = w0 + threadIdx.x; w < w1; w += 256) {
        ull ov = offs[w];
        uint32_t lo = (uint32_t)ov, hi = (uint32_t)(ov >> 32);
        int ob = (int)(((b  < 4) ? (lo >> (8 * b))  : (hi >> (8 * (b  - 4)))) & 0xFF);
        int oe = (int)(((nb < 4) ? (lo >> (8 * nb)) : (hi >> (8 * (nb - 4)))) & 0xFF);
        const uint2* rb = recs + (size_t)w * 64;
        for (int r = ob; r < oe; ++r) {
            uint2 rec = rb[r];
            atomicAdd(&acc[(int)rec.x - base_node], __uint_as_float(rec.y));
        }
    }
    __syncthreads();

    float* pb = partial + ((size_t)b * CCHUNK + c) * BKT_RANGE;
    for (int i = threadIdx.x; i < BKT_RANGE; i += 256) pb[i] = acc[i];
}

__global__ __launch_bounds__(256) void bucket_reduce_kernel(
    const float* __restrict__ partial, float* __restrict__ agg, int N)
{
    int n = blockIdx.x * 256 + threadIdx.x;
    if (n >= N) return;
    int b = n >> BKT_SHIFT, nl = n & (BKT_RANGE - 1);
    const float* p = partial + (size_t)b * CCHUNK * BKT_RANGE + nl;
    float s = 0.f;
#pragma unroll 8
    for (int c = 0; c < CCHUNK; ++c) s += p[(size_t)c * BKT_RANGE];
    agg[n] = s;
}

// ---------------------------------------------------------------------------
// Node v2: 16 nodes per wave, 1 wave per block (3125 blocks -> ~3 waves/SIMD
// of parallelism instead of <1).  Both MLPs fully MFMA with bias-in-K;
// unf passes in-register (after xor-reduce every lane holds unf[its column]).
// ---------------------------------------------------------------------------
__global__ __launch_bounds__(64, 2) void node_mfma2_kernel(
    const float* __restrict__ nf, const float* __restrict__ agg,
    const int* __restrict__ gid,
    const unsigned short* __restrict__ nw1x, const unsigned short* __restrict__ nw2T,
    const float* __restrict__ nb2, const float* __restrict__ nw3, const float* __restrict__ nb3,
    const unsigned short* __restrict__ mw1x, const unsigned short* __restrict__ mw2T,
    const float* __restrict__ mb2, const float* __restrict__ mw3, const float* __restrict__ mb3,
    float* __restrict__ rd, int N)
{
    __shared__ uint2 tile[16][16];

    const int lane = threadIdx.x;
    const int g    = lane >> 4;
    const int eL   = lane & 15;

    const int n0 = blockIdx.x * 16;
    const int nn = n0 + eL < N ? n0 + eL : N - 1;
    const float x0 = nf[nn];
    const float x1 = agg[nn];

    float unf, o;

    // ================= MLP-N =================
    {
        FragU af1[4], af2[4][2];
        f32x4 b2v4[4]; uint32_t w3p[8];
#pragma unroll
        for (int t = 0; t < 4; ++t) {
            uint4 q = *(const uint4*)&nw1x[(t * 16 + eL) * 8];
            af1[t].q = (g == 0) ? q : make_uint4(0, 0, 0, 0);
#pragma unroll
            for (int h = 0; h < 2; ++h)
                af2[t][h].q = *(const uint4*)&nw2T[(t * 16 + eL) * 64 + h * 32 + g * 8];
            int j = t * 16 + g * 4;
            b2v4[t] = *(const f32x4*)&nb2[j];
            f32x4 wv = *(const f32x4*)&nw3[j];
            w3p[2 * t]     = cvt_pk_bf16(wv[0], wv[1]);
            w3p[2 * t + 1] = cvt_pk_bf16(wv[2], wv[3]);
        }
        FragU bin;
        bin.u[0] = (g == 0) ? cvt_pk_bf16(x0, x1) : 0u;    // k=0: nf, k=1: agg
        bin.u[1] = (g == 0) ? cvt_pk_bf16(1.0f, 0.f) : 0u; // k=2: bias slot
        bin.u[2] = 0u; bin.u[3] = 0u;

#pragma unroll
        for (int t = 0; t < 4; ++t) {
            f32x4 h4 = __builtin_amdgcn_mfma_f32_16x16x32_bf16(
                af1[t].v, bin.v, (f32x4){0.f, 0.f, 0.f, 0.f}, 0, 0, 0);
            uint32_t p0 = cvt_pk_bf16(fmaxf(h4[0], 0.f), fmaxf(h4[1], 0.f));
            uint32_t p1 = cvt_pk_bf16(fmaxf(h4[2], 0.f), fmaxf(h4[3], 0.f));
            tile[eL][(4 * t + g) ^ ((eL & 7) << 1)] = make_uint2(p0, p1);
        }
        FragU bf0, bf1;
        {
            const uint4* row = (const uint4*)&tile[eL][0];
            bf0.q = row[(g)     ^ (eL & 7)];
            bf1.q = row[(4 + g) ^ (eL & 7)];
        }
        float p = 0.f;
#pragma unroll
        for (int t = 0; t < 4; ++t) {
            f32x4 ac = __builtin_amdgcn_mfma_f32_16x16x32_bf16(af2[t][0].v, bf0.v, b2v4[t], 0, 0, 0);
            ac = __builtin_amdgcn_mfma_f32_16x16x32_bf16(af2[t][1].v, bf1.v, ac, 0, 0, 0);
            p = fmaf(fmaxf(ac[0], 0.f), bf16lo_f(w3p[2 * t]),     p);
            p = fmaf(fmaxf(ac[1], 0.f), bf16hi_f(w3p[2 * t]),     p);
            p = fmaf(fmaxf(ac[2], 0.f), bf16lo_f(w3p[2 * t + 1]), p);
            p = fmaf(fmaxf(ac[3], 0.f), bf16hi_f(w3p[2 * t + 1]), p);
        }
        p += __shfl_xor(p, 16);
        p += __shfl_xor(p, 32);
        unf = p + nb3[0];
    }

    // ================= MLP-M =================
    {
        FragU af1[4], af2[4][2];
        f32x4 b2v4[4]; uint32_t w3p[8];
#pragma unroll
        for (int t = 0; t < 4; ++t) {
            uint4 q = *(const uint4*)&mw1x[(t * 16 + eL) * 8];
            af1[t].q = (g == 0) ? q : make_uint4(0, 0, 0, 0);
#pragma unroll
            for (int h = 0; h < 2; ++h)
                af2[t][h].q = *(const uint4*)&mw2T[(t * 16 + eL) * 64 + h * 32 + g * 8];
            int j = t * 16 + g * 4;
            b2v4[t] = *(const f32x4*)&mb2[j];
            f32x4 wv = *(const f32x4*)&mw3[j];
            w3p[2 * t]     = cvt_pk_bf16(wv[0], wv[1]);
            w3p[2 * t + 1] = cvt_pk_bf16(wv[2], wv[3]);
        }
        FragU bin;
        bin.u[0] = (g == 0) ? cvt_pk_bf16(unf, 1.0f) : 0u;  // k=0: unf, k=1: bias slot
        bin.u[1] = 0u; bin.u[2] = 0u; bin.u[3] = 0u;

#pragma unroll
        for (int t = 0; t < 4; ++t) {
            f32x4 h4 = __builtin_amdgcn_mfma_f32_16x16x32_bf16(
                af1[t].v, bin.v, (f32x4){0.f, 0.f, 0.f, 0.f}, 0, 0, 0);
            uint32_t p0 = cvt_pk_bf16(fmaxf(h4[0], 0.f), fmaxf(h4[1], 0.f));
            uint32_t p1 = cvt_pk_bf16(fmaxf(h4[2], 0.f), fmaxf(h4[3], 0.f));
            tile[eL][(4 * t + g) ^ ((eL & 7) << 1)] = make_uint2(p0, p1);
        }
        FragU bf0, bf1;
        {
            const uint4* row = (const uint4*)&tile[eL][0];
            bf0.q = row[(g)     ^ (eL & 7)];
            bf1.q = row[(4 + g) ^ (eL & 7)];
        }
        float p = 0.f;
#pragma unroll
        for (int t = 0; t < 4; ++t) {
            f32x4 ac = __builtin_amdgcn_mfma_f32_16x16x32_bf16(af2[t][0].v, bf0.v, b2v4[t], 0, 0, 0);
            ac = __builtin_amdgcn_mfma_f32_16x16x32_bf16(af2[t][1].v, bf1.v, ac, 0, 0, 0);
            p = fmaf(fmaxf(ac[0], 0.f), bf16lo_f(w3p[2 * t]),     p);
            p = fmaf(fmaxf(ac[1], 0.f), bf16hi_f(w3p[2 * t]),     p);
            p = fmaf(fmaxf(ac[2], 0.f), bf16lo_f(w3p[2 * t + 1]), p);
            p = fmaf(fmaxf(ac[3], 0.f), bf16hi_f(w3p[2 * t + 1]), p);
        }
        p += __shfl_xor(p, 16);
        p += __shfl_xor(p, 32);
        o = p + mb3[0];
    }

    float node_out = 1.0f / (1.0f + expf(-o));

    // ---- segmented scan over the 16 sorted-gid nodes (lanes 0..15) ----
    {
        int gg = gid[nn];
        float v = (n0 + eL < N && g == 0) ? node_out : 0.f;
#pragma unroll
        for (int d = 1; d < 16; d <<= 1) {
            float vup = __shfl_up(v, d);
            int   gup = __shfl_up(gg, d);
            if (lane >= d && lane < 16 && gup == gg) v += vup;
        }
        if (lane < 16 && n0 + lane < N) {
            int gdn = __shfl_down(gg, 1);
            bool tail = (lane == 15) || (n0 + lane + 1 >= N) || (gdn != gg);
            if (tail) atomicAdd(&rd[gg], v);
        }
    }
}

__global__ void readout_kernel(const float* __restrict__ rd,
                               float* __restrict__ out, int G)
{
    int g = blockIdx.x * blockDim.x + threadIdx.x;
    if (g < G) out[g] = 1.0f / (1.0f + expf(-rd[g]));
}

extern "C" void kernel_launch(void* const* d_in, const int* in_sizes, int n_in,
                              void* d_out, int out_size, void* d_ws, size_t ws_size,
                              hipStream_t stream)
{
    const float* nf  = (const float*)d_in[0];
    const float* ef  = (const float*)d_in[1];
    const int*   src = (const int*)  d_in[2];
    const int*   dst = (const int*)  d_in[3];
    const int*   gid = (const int*)  d_in[4];

    const float* e_w1 = (const float*)d_in[5];
    const float* e_b1 = (const float*)d_in[6];
    const float* e_w2 = (const float*)d_in[7];
    const float* e_b2 = (const float*)d_in[8];
    const float* e_w3 = (const float*)d_in[9];
    const float* e_b3 = (const float*)d_in[10];

    const float* n_w1 = (const float*)d_in[11];
    const float* n_b1 = (const float*)d_in[12];
    const float* n_w2 = (const float*)d_in[13];
    const float* n_b2 = (const float*)d_in[14];
    const float* n_w3 = (const float*)d_in[15];
    const float* n_b3 = (const float*)d_in[16];

    const float* m_w1 = (const float*)d_in[17];
    const float* m_b1 = (const float*)d_in[18];
    const float* m_w2 = (const float*)d_in[19];
    const float* m_b2 = (const float*)d_in[20];
    const float* m_w3 = (const float*)d_in[21];
    const float* m_b3 = (const float*)d_in[22];

    const int N = in_sizes[0];   // 50000
    const int E = in_sizes[2];   // 1600000
    const int G = out_size;      // 512

    const int NW = (E + 63) / 64;
    const int B  = (N + BKT_RANGE - 1) / BKT_RANGE;

    // ws layout: weights (32KB) | recs | offs | partial | agg | rd
    size_t wts_b  = 32 * 1024;
    size_t recs_b = (size_t)NW * 64 * sizeof(uint2);
    size_t offs_b = (size_t)NW * sizeof(ull);
    size_t part_b = (size_t)B * CCHUNK * BKT_RANGE * sizeof(float);
    size_t need   = wts_b + recs_b + offs_b + part_b + ((size_t)N + G) * sizeof(float);
    bool bucketok = (B <= 8) && (need <= ws_size);

    char* wp = (char*)d_ws;
    unsigned short* w1x  = (unsigned short*)(wp);            // 1KB
    unsigned short* nw1x = (unsigned short*)(wp + 1024);
    unsigned short* mw1x = (unsigned short*)(wp + 2048);
    unsigned short* w2T  = (unsigned short*)(wp + 4096);     // 8KB
    unsigned short* nw2T = (unsigned short*)(wp + 4096 + 8192);
    unsigned short* mw2T = (unsigned short*)(wp + 4096 + 16384);

    float* out = (float*)d_out;

    prep_kernel<<<16, 256, 0, stream>>>(
        e_w1, e_b1, e_w2, n_w1, n_b1, n_w2, m_w1, m_b1, m_w2,
        w1x, w2T, nw1x, nw2T, mw1x, mw2T);

    if (bucketok) {
        uint2* recs    = (uint2*)(wp + wts_b);
        ull*   offs    = (ull*)(wp + wts_b + recs_b);
        float* partial = (float*)(wp + wts_b + recs_b + offs_b);
        float* agg     = (float*)(wp + wts_b + recs_b + offs_b + part_b);
        float* rd      = agg + N;

        hipMemsetAsync(rd, 0, (size_t)G * sizeof(float), stream);

        edge_mfma2_kernel<<<(E + 255) / 256, 256, 0, stream>>>(
            nf, ef, src, dst, w1x, w2T, e_b2, e_w3, e_b3,
            recs, offs, nullptr, E, B, 0);

        bucket_accum_kernel<<<B * CCHUNK, 256, 0, stream>>>(
            recs, offs, partial, NW, B);

        bucket_reduce_kernel<<<(N + 255) / 256, 256, 0, stream>>>(
            partial, agg, N);

        node_mfma2_kernel<<<(N + 15) / 16, 64, 0, stream>>>(
            nf, agg, gid,
            nw1x, nw2T, n_b2, n_w3, n_b3,
            mw1x, mw2T, m_b2, m_w3, m_b3,
            rd, N);

        readout_kernel<<<(G + 255) / 256, 256, 0, stream>>>(rd, out, G);
    } else {
        float* agg = (float*)(wp + wts_b);
        float* rd  = agg + N;

        hipMemsetAsync(agg, 0, ((size_t)N + G) * sizeof(float), stream);

        edge_mfma2_kernel<<<(E + 255) / 256, 256, 0, stream>>>(
            nf, ef, src, dst, w1x, w2T, e_b2, e_w3, e_b3,
            nullptr, nullptr, agg, E, B, 1);

        node_mfma2_kernel<<<(N + 15) / 16, 64, 0, stream>>>(
            nf, agg, gid,
            nw1x, nw2T, n_b2, n_w3, n_b3,
            mw1x, mw2T, m_b2, m_w3, m_b3,
            rd, N);

        readout_kernel<<<(G + 255) / 256, 256, 0, stream>>>(rd, out, G);
    }
}

// Round 8
// 79.492 us; speedup vs baseline: 1.0994x; 1.0994x over previous
//
#include <hip/hip_runtime.h>
#include <math.h>

#define HID 64
#define BKT_SHIFT 13                 // 8192 nodes per bucket
#define BKT_RANGE 8192
#define CCHUNK 32                    // wave-chunks per bucket in phase B

typedef __attribute__((ext_vector_type(8))) short short8;
typedef __attribute__((ext_vector_type(4))) float f32x4;
typedef unsigned long long ull;

union FragU {
    uint4 q;
    short8 v;
    uint32_t u[4];
};

__device__ __forceinline__ uint32_t cvt_pk_bf16(float lo, float hi) {
    uint32_t r;
    asm("v_cvt_pk_bf16_f32 %0, %1, %2" : "=v"(r) : "v"(lo), "v"(hi));
    return r;
}
__device__ __forceinline__ float bf16lo_f(uint32_t u) { return __uint_as_float(u << 16); }
__device__ __forceinline__ float bf16hi_f(uint32_t u) { return __uint_as_float(u & 0xFFFF0000u); }
__device__ __forceinline__ unsigned short bf16_of(float v) {
    return (unsigned short)(cvt_pk_bf16(v, 0.f) & 0xFFFFu);
}

// ---------------------------------------------------------------------------
// Prep: bf16-transposed weights (identical to round 7).
// ---------------------------------------------------------------------------
__global__ void prep_kernel(
    const float* __restrict__ w1,  const float* __restrict__ b1,  const float* __restrict__ w2,
    const float* __restrict__ nw1, const float* __restrict__ nb1, const float* __restrict__ nw2,
    const float* __restrict__ mw1, const float* __restrict__ mb1, const float* __restrict__ mw2,
    unsigned short* __restrict__ w1x,  unsigned short* __restrict__ w2T,
    unsigned short* __restrict__ nw1x, unsigned short* __restrict__ nw2T,
    unsigned short* __restrict__ mw1x, unsigned short* __restrict__ mw2T)
{
    int t = blockIdx.x * 256 + threadIdx.x;
    if (t < 4096) {
        int j = t >> 6, k = t & 63;
        w2T [t] = bf16_of(w2 [k * HID + j]);
        nw2T[t] = bf16_of(nw2[k * HID + j]);
        mw2T[t] = bf16_of(mw2[k * HID + j]);
    }
    if (t < 512) {
        int j = t >> 3, k = t & 7;
        float ve = k == 0 ? w1[j] : k == 1 ? w1[HID + j] : k == 2 ? w1[2 * HID + j] : k == 3 ? b1[j] : 0.f;
        float vn = k == 0 ? nw1[j] : k == 1 ? nw1[HID + j] : k == 2 ? nb1[j] : 0.f;
        float vm = k == 0 ? mw1[j] : k == 1 ? mb1[j] : 0.f;
        w1x [t] = bf16_of(ve);
        nw1x[t] = bf16_of(vn);
        mw1x[t] = bf16_of(vm);
    }
}

// ---------------------------------------------------------------------------
// Edge v4: PERSISTENT blocks + software pipeline + phase-split.
// Weights loaded once per block. Per batch (64 edges/wave):
//   shfl-distribute inputs -> issue next batch src/dst/ef loads ->
//   L1 phase: 16 indep MFMA into tile[wid][s] (32KB/block) ->
//   issue next batch nf gathers -> L2 phase: 32 MFMA + epilogue ->
//   bucket append (mode 0) / atomicAdd (mode 1).
// ---------------------------------------------------------------------------
__global__ __launch_bounds__(256, 2) void edge_mfma3_kernel(
    const float* __restrict__ nf, const float* __restrict__ ef,
    const int* __restrict__ src, const int* __restrict__ dst,
    const unsigned short* __restrict__ w1x, const unsigned short* __restrict__ w2T,
    const float* __restrict__ b2, const float* __restrict__ w3, const float* __restrict__ b3,
    uint2* __restrict__ recs, ull* __restrict__ offs,
    float* __restrict__ aggFb, int E, int B, int nbatch, int mode)
{
    __shared__ uint2 tile[4][4][16][16];   // [wave][set][row][chunk] = 32 KB

    const int tid  = threadIdx.x;
    const int lane = tid & 63;
    const int wid  = tid >> 6;
    const int g    = lane >> 4;
    const int eL   = lane & 15;

    // ---- weights: once per block ----
    FragU af1[4];
#pragma unroll
    for (int t = 0; t < 4; ++t) {
        uint4 q = *(const uint4*)&w1x[(t * 16 + eL) * 8];
        af1[t].q = (g == 0) ? q : make_uint4(0, 0, 0, 0);
    }
    FragU af2[4][2];
#pragma unroll
    for (int t = 0; t < 4; ++t)
#pragma unroll
        for (int h = 0; h < 2; ++h)
            af2[t][h].q = *(const uint4*)&w2T[(t * 16 + eL) * 64 + h * 32 + g * 8];

    f32x4 b2v4[4];
    uint32_t w3p[8];
#pragma unroll
    for (int t = 0; t < 4; ++t) {
        int j = t * 16 + g * 4;
        b2v4[t] = *(const f32x4*)&b2[j];
        f32x4 wv = *(const f32x4*)&w3[j];
        w3p[2 * t]     = cvt_pk_bf16(wv[0], wv[1]);
        w3p[2 * t + 1] = cvt_pk_bf16(wv[2], wv[3]);
    }
    const float b3c = b3[0];

    // ---- first batch loads ----
    int bi   = blockIdx.x;
    if (bi >= nbatch) return;
    int eidx = bi * 256 + tid;
    int ei   = eidx < E ? eidx : E - 1;
    int dcur = dst[ei];
    float a  = nf[src[ei]];
    float b  = nf[dcur];
    float c  = ef[ei];

    for (;;) {
        // ---- prefetch next batch indices (issued early, consumed late) ----
        const int nbi   = bi + gridDim.x;
        const bool hn   = nbi < nbatch;
        const int neidx = hn ? nbi * 256 + tid : eidx;
        const int nei   = neidx < E ? neidx : E - 1;
        const int ns    = src[nei];
        const int nd    = dst[nei];
        const float ncf = ef[nei];

        // ---- L1 phase: 16 independent MFMAs into per-set tiles ----
#pragma unroll
        for (int s = 0; s < 4; ++s) {
            float av = __shfl(a, s * 16 + eL);
            float bv = __shfl(b, s * 16 + eL);
            float cv = __shfl(c, s * 16 + eL);
            FragU bin;
            bin.u[0] = (g == 0) ? cvt_pk_bf16(av, bv) : 0u;
            bin.u[1] = (g == 0) ? cvt_pk_bf16(cv, 1.0f) : 0u;
            bin.u[2] = 0u; bin.u[3] = 0u;
#pragma unroll
            for (int t = 0; t < 4; ++t) {
                f32x4 h4 = __builtin_amdgcn_mfma_f32_16x16x32_bf16(
                    af1[t].v, bin.v, (f32x4){0.f, 0.f, 0.f, 0.f}, 0, 0, 0);
                uint32_t p0 = cvt_pk_bf16(fmaxf(h4[0], 0.f), fmaxf(h4[1], 0.f));
                uint32_t p1 = cvt_pk_bf16(fmaxf(h4[2], 0.f), fmaxf(h4[3], 0.f));
                tile[wid][s][eL][(4 * t + g) ^ ((eL & 7) << 1)] = make_uint2(p0, p1);
            }
        }

        // ---- prefetch next batch gathers (hidden under L2 phase) ----
        const float na = nf[ns];
        const float nb = nf[nd];

        // ---- L2 phase: 4 independent sets of 8 MFMA + epilogue ----
        float mymsg = 0.f;
#pragma unroll
        for (int s = 0; s < 4; ++s) {
            const uint4* row = (const uint4*)&tile[wid][s][eL][0];
            FragU bf0, bf1;
            bf0.q = row[(g)     ^ (eL & 7)];
            bf1.q = row[(4 + g) ^ (eL & 7)];

            float p = 0.f;
#pragma unroll
            for (int t = 0; t < 4; ++t) {
                f32x4 ac = __builtin_amdgcn_mfma_f32_16x16x32_bf16(af2[t][0].v, bf0.v, b2v4[t], 0, 0, 0);
                ac = __builtin_amdgcn_mfma_f32_16x16x32_bf16(af2[t][1].v, bf1.v, ac, 0, 0, 0);
                p = fmaf(fmaxf(ac[0], 0.f), bf16lo_f(w3p[2 * t]),     p);
                p = fmaf(fmaxf(ac[1], 0.f), bf16hi_f(w3p[2 * t]),     p);
                p = fmaf(fmaxf(ac[2], 0.f), bf16lo_f(w3p[2 * t + 1]), p);
                p = fmaf(fmaxf(ac[3], 0.f), bf16hi_f(w3p[2 * t + 1]), p);
            }
            p += __shfl_xor(p, 16);
            p += __shfl_xor(p, 32);
            if (s == g) mymsg = p + b3c;
        }

        const bool valid = eidx < E;

        if (mode == 1) {
            if (valid) atomicAdd(&aggFb[dcur], mymsg);
        } else {
            // ---- bucket append: coalesced wave-private, zero atomics ----
            const int bkt = dcur >> BKT_SHIFT;
            const ull lt = (1ull << lane) - 1;
            int myslot = 0;
            int off = 0;
            uint32_t pack_lo = 0, pack_hi = 0;
            for (int bb = 0; bb < B; ++bb) {
                if (bb < 4) pack_lo |= (uint32_t)off << (8 * bb);
                else        pack_hi |= (uint32_t)off << (8 * (bb - 4));
                ull m = __ballot(valid && bkt == bb);
                if (valid && bkt == bb) myslot = off + (int)__popcll(m & lt);
                off += (int)__popcll(m);
            }
            pack_hi |= (uint32_t)off << 24;

            const size_t wgl = (size_t)bi * 4 + wid;
            if (valid) recs[wgl * 64 + myslot] = make_uint2((uint32_t)dcur, __float_as_uint(mymsg));
            if (lane == 0) offs[wgl] = ((ull)pack_hi << 32) | (ull)pack_lo;
        }

        if (!hn) break;
        bi = nbi; eidx = neidx; ei = nei;
        a = na; b = nb; c = ncf; dcur = nd;
    }
}

// ---------------------------------------------------------------------------
// Phase B: block (b,c) accumulates bucket b's records from wave-chunk c into
// a 32KB LDS array (LDS atomics), then writes a dense partial plane.
// ---------------------------------------------------------------------------
__global__ __launch_bounds__(256) void bucket_accum_kernel(
    const uint2* __restrict__ recs, const ull* __restrict__ offs,
    float* __restrict__ partial, int NW, int B)
{
    __shared__ float acc[BKT_RANGE];

    const int b = blockIdx.x / CCHUNK;
    const int c = blockIdx.x % CCHUNK;

    for (int i = threadIdx.x; i < BKT_RANGE; i += 256) acc[i] = 0.f;
    __syncthreads();

    const int wpc = (NW + CCHUNK - 1) / CCHUNK;
    const int w0 = c * wpc;
    const int w1 = (w0 + wpc < NW) ? w0 + wpc : NW;
    const int nb = b + 1;
    const int base_node = b << BKT_SHIFT;

    for (int w = w0 + threadIdx.x; w < w1; w += 256) {
        ull ov = offs[w];
        uint32_t lo = (uint32_t)ov, hi = (uint32_t)(ov >> 32);
        int ob = (int)(((b  < 4) ? (lo >> (8 * b))  : (hi >> (8 * (b  - 4)))) & 0xFF);
        int oe = (int)(((nb < 4) ? (lo >> (8 * nb)) : (hi >> (8 * (nb - 4)))) & 0xFF);
        const uint2* rb = recs + (size_t)w * 64;
        for (int r = ob; r < oe; ++r) {
            uint2 rec = rb[r];
            atomicAdd(&acc[(int)rec.x - base_node], __uint_as_float(rec.y));
        }
    }
    __syncthreads();

    float* pb = partial + ((size_t)b * CCHUNK + c) * BKT_RANGE;
    for (int i = threadIdx.x; i < BKT_RANGE; i += 256) pb[i] = acc[i];
}

__global__ __launch_bounds__(256) void bucket_reduce_kernel(
    const float* __restrict__ partial, float* __restrict__ agg, int N)
{
    int n = blockIdx.x * 256 + threadIdx.x;
    if (n >= N) return;
    int b = n >> BKT_SHIFT, nl = n & (BKT_RANGE - 1);
    const float* p = partial + (size_t)b * CCHUNK * BKT_RANGE + nl;
    float s = 0.f;
#pragma unroll 8
    for (int c = 0; c < CCHUNK; ++c) s += p[(size_t)c * BKT_RANGE];
    agg[n] = s;
}

// ---------------------------------------------------------------------------
// Node v3: 4-wave blocks, 64 nodes per wave (phase-split, same as edge).
// unf passes in-register via the if(s==g) trick. Weights amortized over
// 256 nodes/block. Segmented 64-lane scan over sorted gid -> tail atomics.
// ---------------------------------------------------------------------------
__global__ __launch_bounds__(256, 2) void node_mfma3_kernel(
    const float* __restrict__ nf, const float* __restrict__ agg,
    const int* __restrict__ gid,
    const unsigned short* __restrict__ nw1x, const unsigned short* __restrict__ nw2T,
    const float* __restrict__ nb2, const float* __restrict__ nw3, const float* __restrict__ nb3,
    const unsigned short* __restrict__ mw1x, const unsigned short* __restrict__ mw2T,
    const float* __restrict__ mb2, const float* __restrict__ mw3, const float* __restrict__ mb3,
    float* __restrict__ rd, int N)
{
    __shared__ uint2 tile[4][4][16][16];   // 32 KB

    const int tid  = threadIdx.x;
    const int lane = tid & 63;
    const int wid  = tid >> 6;
    const int g    = lane >> 4;
    const int eL   = lane & 15;

    const int idx = blockIdx.x * 256 + tid;
    const int i   = idx < N ? idx : N - 1;
    const float x0 = nf[i];
    const float x1 = agg[i];
    const int   gg = gid[i];

    float myunf = 0.f, o = 0.f;

    // ================= MLP-N: [nf, agg] -> unf =================
    {
        FragU af1[4], af2[4][2];
        f32x4 b2v4[4]; uint32_t w3p[8];
#pragma unroll
        for (int t = 0; t < 4; ++t) {
            uint4 q = *(const uint4*)&nw1x[(t * 16 + eL) * 8];
            af1[t].q = (g == 0) ? q : make_uint4(0, 0, 0, 0);
#pragma unroll
            for (int h = 0; h < 2; ++h)
                af2[t][h].q = *(const uint4*)&nw2T[(t * 16 + eL) * 64 + h * 32 + g * 8];
            int j = t * 16 + g * 4;
            b2v4[t] = *(const f32x4*)&nb2[j];
            f32x4 wv = *(const f32x4*)&nw3[j];
            w3p[2 * t]     = cvt_pk_bf16(wv[0], wv[1]);
            w3p[2 * t + 1] = cvt_pk_bf16(wv[2], wv[3]);
        }

#pragma unroll
        for (int s = 0; s < 4; ++s) {
            float av = __shfl(x0, s * 16 + eL);
            float bv = __shfl(x1, s * 16 + eL);
            FragU bin;
            bin.u[0] = (g == 0) ? cvt_pk_bf16(av, bv) : 0u;
            bin.u[1] = (g == 0) ? cvt_pk_bf16(1.0f, 0.f) : 0u;
            bin.u[2] = 0u; bin.u[3] = 0u;
#pragma unroll
            for (int t = 0; t < 4; ++t) {
                f32x4 h4 = __builtin_amdgcn_mfma_f32_16x16x32_bf16(
                    af1[t].v, bin.v, (f32x4){0.f, 0.f, 0.f, 0.f}, 0, 0, 0);
                uint32_t p0 = cvt_pk_bf16(fmaxf(h4[0], 0.f), fmaxf(h4[1], 0.f));
                uint32_t p1 = cvt_pk_bf16(fmaxf(h4[2], 0.f), fmaxf(h4[3], 0.f));
                tile[wid][s][eL][(4 * t + g) ^ ((eL & 7) << 1)] = make_uint2(p0, p1);
            }
        }
#pragma unroll
        for (int s = 0; s < 4; ++s) {
            const uint4* row = (const uint4*)&tile[wid][s][eL][0];
            FragU bf0, bf1;
            bf0.q = row[(g)     ^ (eL & 7)];
            bf1.q = row[(4 + g) ^ (eL & 7)];
            float p = 0.f;
#pragma unroll
            for (int t = 0; t < 4; ++t) {
                f32x4 ac = __builtin_amdgcn_mfma_f32_16x16x32_bf16(af2[t][0].v, bf0.v, b2v4[t], 0, 0, 0);
                ac = __builtin_amdgcn_mfma_f32_16x16x32_bf16(af2[t][1].v, bf1.v, ac, 0, 0, 0);
                p = fmaf(fmaxf(ac[0], 0.f), bf16lo_f(w3p[2 * t]),     p);
                p = fmaf(fmaxf(ac[1], 0.f), bf16hi_f(w3p[2 * t]),     p);
                p = fmaf(fmaxf(ac[2], 0.f), bf16lo_f(w3p[2 * t + 1]), p);
                p = fmaf(fmaxf(ac[3], 0.f), bf16hi_f(w3p[2 * t + 1]), p);
            }
            p += __shfl_xor(p, 16);
            p += __shfl_xor(p, 32);
            if (s == g) myunf = p + nb3[0];
        }
    }

    // ================= MLP-M: unf -> o =================
    {
        FragU af1[4], af2[4][2];
        f32x4 b2v4[4]; uint32_t w3p[8];
#pragma unroll
        for (int t = 0; t < 4; ++t) {
            uint4 q = *(const uint4*)&mw1x[(t * 16 + eL) * 8];
            af1[t].q = (g == 0) ? q : make_uint4(0, 0, 0, 0);
#pragma unroll
            for (int h = 0; h < 2; ++h)
                af2[t][h].q = *(const uint4*)&mw2T[(t * 16 + eL) * 64 + h * 32 + g * 8];
            int j = t * 16 + g * 4;
            b2v4[t] = *(const f32x4*)&mb2[j];
            f32x4 wv = *(const f32x4*)&mw3[j];
            w3p[2 * t]     = cvt_pk_bf16(wv[0], wv[1]);
            w3p[2 * t + 1] = cvt_pk_bf16(wv[2], wv[3]);
        }

#pragma unroll
        for (int s = 0; s < 4; ++s) {
            float uv = __shfl(myunf, s * 16 + eL);
            FragU bin;
            bin.u[0] = (g == 0) ? cvt_pk_bf16(uv, 1.0f) : 0u;
            bin.u[1] = 0u; bin.u[2] = 0u; bin.u[3] = 0u;
#pragma unroll
            for (int t = 0; t < 4; ++t) {
                f32x4 h4 = __builtin_amdgcn_mfma_f32_16x16x32_bf16(
                    af1[t].v, bin.v, (f32x4){0.f, 0.f, 0.f, 0.f}, 0, 0, 0);
                uint32_t p0 = cvt_pk_bf16(fmaxf(h4[0], 0.f), fmaxf(h4[1], 0.f));
                uint32_t p1 = cvt_pk_bf16(fmaxf(h4[2], 0.f), fmaxf(h4[3], 0.f));
                tile[wid][s][eL][(4 * t + g) ^ ((eL & 7) << 1)] = make_uint2(p0, p1);
            }
        }
#pragma unroll
        for (int s = 0; s < 4; ++s) {
            const uint4* row = (const uint4*)&tile[wid][s][eL][0];
            FragU bf0, bf1;
            bf0.q = row[(g)     ^ (eL & 7)];
            bf1.q = row[(4 + g) ^ (eL & 7)];
            float p = 0.f;
#pragma unroll
            for (int t = 0; t < 4; ++t) {
                f32x4 ac = __builtin_amdgcn_mfma_f32_16x16x32_bf16(af2[t][0].v, bf0.v, b2v4[t], 0, 0, 0);
                ac = __builtin_amdgcn_mfma_f32_16x16x32_bf16(af2[t][1].v, bf1.v, ac, 0, 0, 0);
                p = fmaf(fmaxf(ac[0], 0.f), bf16lo_f(w3p[2 * t]),     p);
                p = fmaf(fmaxf(ac[1], 0.f), bf16hi_f(w3p[2 * t]),     p);
                p = fmaf(fmaxf(ac[2], 0.f), bf16lo_f(w3p[2 * t + 1]), p);
                p = fmaf(fmaxf(ac[3], 0.f), bf16hi_f(w3p[2 * t + 1]), p);
            }
            p += __shfl_xor(p, 16);
            p += __shfl_xor(p, 32);
            if (s == g) o = p + mb3[0];
        }
    }

    const float node_out = 1.0f / (1.0f + expf(-o));

    // ---- segmented reduction over sorted gid, one atomic per run tail ----
    {
        const bool ok = idx < N;
        float v = ok ? node_out : 0.0f;
        int ggv = gg;
#pragma unroll
        for (int d = 1; d < 64; d <<= 1) {
            float vup = __shfl_up(v, d);
            int   gup = __shfl_up(ggv, d);
            if (lane >= d && gup == ggv) v += vup;
        }
        int gdn = __shfl_down(ggv, 1);
        bool tail = (lane == 63) || (gdn != ggv);
        if (tail)
            atomicAdd(&rd[ggv], v);
    }
}

__global__ void readout_kernel(const float* __restrict__ rd,
                               float* __restrict__ out, int G)
{
    int g = blockIdx.x * blockDim.x + threadIdx.x;
    if (g < G) out[g] = 1.0f / (1.0f + expf(-rd[g]));
}

extern "C" void kernel_launch(void* const* d_in, const int* in_sizes, int n_in,
                              void* d_out, int out_size, void* d_ws, size_t ws_size,
                              hipStream_t stream)
{
    const float* nf  = (const float*)d_in[0];
    const float* ef  = (const float*)d_in[1];
    const int*   src = (const int*)  d_in[2];
    const int*   dst = (const int*)  d_in[3];
    const int*   gid = (const int*)  d_in[4];

    const float* e_w1 = (const float*)d_in[5];
    const float* e_b1 = (const float*)d_in[6];
    const float* e_w2 = (const float*)d_in[7];
    const float* e_b2 = (const float*)d_in[8];
    const float* e_w3 = (const float*)d_in[9];
    const float* e_b3 = (const float*)d_in[10];

    const float* n_w1 = (const float*)d_in[11];
    const float* n_b1 = (const float*)d_in[12];
    const float* n_w2 = (const float*)d_in[13];
    const float* n_b2 = (const float*)d_in[14];
    const float* n_w3 = (const float*)d_in[15];
    const float* n_b3 = (const float*)d_in[16];

    const float* m_w1 = (const float*)d_in[17];
    const float* m_b1 = (const float*)d_in[18];
    const float* m_w2 = (const float*)d_in[19];
    const float* m_b2 = (const float*)d_in[20];
    const float* m_w3 = (const float*)d_in[21];
    const float* m_b3 = (const float*)d_in[22];

    const int N = in_sizes[0];   // 50000
    const int E = in_sizes[2];   // 1600000
    const int G = out_size;      // 512

    const int nbatch = (E + 255) / 256;
    const int NW = (E + 63) / 64;
    const int B  = (N + BKT_RANGE - 1) / BKT_RANGE;

    size_t wts_b  = 32 * 1024;
    size_t recs_b = (size_t)NW * 64 * sizeof(uint2);
    size_t offs_b = (size_t)NW * sizeof(ull);
    size_t part_b = (size_t)B * CCHUNK * BKT_RANGE * sizeof(float);
    size_t need   = wts_b + recs_b + offs_b + part_b + ((size_t)N + G) * sizeof(float);
    bool bucketok = (B <= 8) && (need <= ws_size);

    char* wp = (char*)d_ws;
    unsigned short* w1x  = (unsigned short*)(wp);
    unsigned short* nw1x = (unsigned short*)(wp + 1024);
    unsigned short* mw1x = (unsigned short*)(wp + 2048);
    unsigned short* w2T  = (unsigned short*)(wp + 4096);
    unsigned short* nw2T = (unsigned short*)(wp + 4096 + 8192);
    unsigned short* mw2T = (unsigned short*)(wp + 4096 + 16384);

    float* out = (float*)d_out;

    prep_kernel<<<16, 256, 0, stream>>>(
        e_w1, e_b1, e_w2, n_w1, n_b1, n_w2, m_w1, m_b1, m_w2,
        w1x, w2T, nw1x, nw2T, mw1x, mw2T);

    int egrid = nbatch < 1024 ? nbatch : 1024;

    if (bucketok) {
        uint2* recs    = (uint2*)(wp + wts_b);
        ull*   offs    = (ull*)(wp + wts_b + recs_b);
        float* partial = (float*)(wp + wts_b + recs_b + offs_b);
        float* agg     = (float*)(wp + wts_b + recs_b + offs_b + part_b);
        float* rd      = agg + N;

        hipMemsetAsync(rd, 0, (size_t)G * sizeof(float), stream);

        edge_mfma3_kernel<<<egrid, 256, 0, stream>>>(
            nf, ef, src, dst, w1x, w2T, e_b2, e_w3, e_b3,
            recs, offs, nullptr, E, B, nbatch, 0);

        bucket_accum_kernel<<<B * CCHUNK, 256, 0, stream>>>(
            recs, offs, partial, NW, B);

        bucket_reduce_kernel<<<(N + 255) / 256, 256, 0, stream>>>(
            partial, agg, N);

        node_mfma3_kernel<<<(N + 255) / 256, 256, 0, stream>>>(
            nf, agg, gid,
            nw1x, nw2T, n_b2, n_w3, n_b3,
            mw1x, mw2T, m_b2, m_w3, m_b3,
            rd, N);

        readout_kernel<<<(G + 255) / 256, 256, 0, stream>>>(rd, out, G);
    } else {
        float* agg = (float*)(wp + wts_b);
        float* rd  = agg + N;

        hipMemsetAsync(agg, 0, ((size_t)N + G) * sizeof(float), stream);

        edge_mfma3_kernel<<<egrid, 256, 0, stream>>>(
            nf, ef, src, dst, w1x, w2T, e_b2, e_w3, e_b3,
            nullptr, nullptr, agg, E, B, nbatch, 1);

        node_mfma3_kernel<<<(N + 255) / 256, 256, 0, stream>>>(
            nf, agg, gid,
            nw1x, nw2T, n_b2, n_w3, n_b3,
            mw1x, mw2T, m_b2, m_w3, m_b3,
            rd, N);

        readout_kernel<<<(G + 255) / 256, 256, 0, stream>>>(rd, out, G);
    }
}